// Round 8
// baseline (272.251 us; speedup 1.0000x reference)
//
#include <hip/hip_runtime.h>

#define NH    16
#define DK    64
#define DIM   1024
#define BATCH 2
#define SEQ   2048
#define MROWS (BATCH*SEQ)   // 4096
#define QSCALE 0.18033688011112043f   // 0.125 * log2(e): folded into Q projection
#define SENT   -44.0f                 // sentinel in log2 domain; exp2(-44)=5.68e-14
#define PCONST 5.684341886080802e-14f // exp2(-44)

typedef unsigned short bfraw;
typedef __attribute__((ext_vector_type(8))) __bf16 bf16x8;
typedef __attribute__((ext_vector_type(4))) __bf16 bf16x4;
typedef __attribute__((ext_vector_type(8))) unsigned short u16x8;
typedef __attribute__((ext_vector_type(4))) unsigned short u16x4;
typedef __attribute__((ext_vector_type(4))) short s16x4;
typedef __attribute__((ext_vector_type(4))) float f32x4;

__device__ __forceinline__ float bf2f(bfraw u) {
    union { unsigned int i; float f; } x; x.i = ((unsigned int)u) << 16; return x.f;
}
__device__ __forceinline__ bfraw f2bf(float f) {          // RNE
    union { float f; unsigned int i; } x; x.f = f;
    unsigned int r = x.i + 0x7FFFu + ((x.i >> 16) & 1u);
    return (bfraw)(r >> 16);
}
__device__ __forceinline__ float fexp2(float x) {
#if __has_builtin(__builtin_amdgcn_exp2f)
    return __builtin_amdgcn_exp2f(x);
#else
    return exp2f(x);
#endif
}

// K=16 bf16 MFMA: D = A(16x16) * B(16x16) + C.
__device__ __forceinline__ f32x4 mfma16(s16x4 a, s16x4 b, f32x4 c) {
#if __has_builtin(__builtin_amdgcn_mfma_f32_16x16x16_bf16)
    union { s16x4 s; bf16x4 h; } ua, ub; ua.s = a; ub.s = b;
    return __builtin_amdgcn_mfma_f32_16x16x16_bf16(ua.h, ub.h, c, 0, 0, 0);
#elif __has_builtin(__builtin_amdgcn_mfma_f32_16x16x16bf16_1k)
    return __builtin_amdgcn_mfma_f32_16x16x16bf16_1k(a, b, c, 0, 0, 0);
#else
    asm("v_mfma_f32_16x16x16_bf16 %0, %1, %2, %0" : "+v"(c) : "v"(a), "v"(b));
    return c;
#endif
}

// ---------------- fp32 -> bf16 convert pass ----------------
__global__ __launch_bounds__(256) void cvt_kernel(
        const float* __restrict__ x0, const float* __restrict__ x1, const float* __restrict__ x2,
        const float* __restrict__ w0, const float* __restrict__ w1, const float* __restrict__ w2,
        const float* __restrict__ w3, bfraw* __restrict__ Xb, bfraw* __restrict__ Wb) {
    const int t = blockIdx.y;
    const float* src; bfraw* dst; int n;
    if (t < 3) { src = (t == 0) ? x0 : (t == 1) ? x1 : x2; dst = Xb + t * (MROWS * DIM); n = MROWS * DIM; }
    else { int u = t - 3; src = (u == 0) ? w0 : (u == 1) ? w1 : (u == 2) ? w2 : w3;
           dst = Wb + u * (DIM * DIM); n = DIM * DIM; }
    int idx = (blockIdx.x * 256 + threadIdx.x) * 8;
    if (idx >= n) return;
    f32x4 a = *(const f32x4*)(src + idx);
    f32x4 b = *(const f32x4*)(src + idx + 4);
    u16x8 o;
    #pragma unroll
    for (int j = 0; j < 4; j++) { o[j] = f2bf(a[j]); o[4 + j] = f2bf(b[j]); }
    *(u16x8*)(dst + idx) = o;
}

// ---------------- 128x128 MFMA GEMM, BK=64 ----------------
// Double-buffered LDS (ONE barrier per K-step) + 2-deep register prefetch.
__device__ __forceinline__ void gemm128(const bfraw* __restrict__ A, const bfraw* __restrict__ B,
                                        int m0, int n0, f32x4 acc[4][4]) {
    __shared__ __align__(16) bfraw As[2][128 * 64];
    __shared__ __align__(16) bfraw Bs[2][128 * 64];
    const int tid = threadIdx.x, wave = tid >> 6;
    const int lane = tid & 63, lrow = lane & 15, quad = lane >> 4;
    const int wy = wave >> 1, wx = wave & 1;
    const int swz = lrow & 7;
    const int srow = tid >> 2;
    const int cg0  = (tid & 3) << 1;
    const int gc   = cg0 << 3;
    const int e7   = srow & 7;
    const int o0 = ((cg0 ^ e7) << 3), o1 = (((cg0 | 1) ^ e7) << 3);

    const bfraw* pa0 = A + (m0 + srow) * DIM + gc;
    const bfraw* pa1 = A + (m0 + 64 + srow) * DIM + gc;
    const bfraw* pb0 = B + (n0 + srow) * DIM + gc;
    const bfraw* pb1 = B + (n0 + 64 + srow) * DIM + gc;

    #pragma unroll
    for (int i = 0; i < 4; i++)
        #pragma unroll
        for (int j = 0; j < 4; j++) { f32x4 z = {0.f, 0.f, 0.f, 0.f}; acc[i][j] = z; }

    u16x8 ha0[4], hb0[4], ha1[4], hb1[4];

    auto LOAD = [&](u16x8 ha[4], u16x8 hb[4], int kk) {
        ha[0] = *(const u16x8*)(pa0 + kk);     ha[1] = *(const u16x8*)(pa0 + kk + 8);
        ha[2] = *(const u16x8*)(pa1 + kk);     ha[3] = *(const u16x8*)(pa1 + kk + 8);
        hb[0] = *(const u16x8*)(pb0 + kk);     hb[1] = *(const u16x8*)(pb0 + kk + 8);
        hb[2] = *(const u16x8*)(pb1 + kk);     hb[3] = *(const u16x8*)(pb1 + kk + 8);
    };
    auto STORE = [&](bfraw* Ad, bfraw* Bd, u16x8 ha[4], u16x8 hb[4]) {
        *(u16x8*)&Ad[srow * 64 + o0]        = ha[0];
        *(u16x8*)&Ad[srow * 64 + o1]        = ha[1];
        *(u16x8*)&Ad[(64 + srow) * 64 + o0] = ha[2];
        *(u16x8*)&Ad[(64 + srow) * 64 + o1] = ha[3];
        *(u16x8*)&Bd[srow * 64 + o0]        = hb[0];
        *(u16x8*)&Bd[srow * 64 + o1]        = hb[1];
        *(u16x8*)&Bd[(64 + srow) * 64 + o0] = hb[2];
        *(u16x8*)&Bd[(64 + srow) * 64 + o1] = hb[3];
    };
    auto COMPUTE = [&](const bfraw* Ad, const bfraw* Bd) {
        #pragma unroll
        for (int ks = 0; ks < 2; ks++) {
            const int c = (ks << 2) | quad;
            bf16x8 af[4], bfg[4];
            #pragma unroll
            for (int mi = 0; mi < 4; mi++)
                af[mi] = *(const bf16x8*)&Ad[(wy * 64 + mi * 16 + lrow) * 64 + ((c ^ swz) << 3)];
            #pragma unroll
            for (int ni = 0; ni < 4; ni++)
                bfg[ni] = *(const bf16x8*)&Bd[(wx * 64 + ni * 16 + lrow) * 64 + ((c ^ swz) << 3)];
            #pragma unroll
            for (int mi = 0; mi < 4; mi++)
                #pragma unroll
                for (int ni = 0; ni < 4; ni++)
                    acc[mi][ni] = __builtin_amdgcn_mfma_f32_16x16x32_bf16(af[mi], bfg[ni], acc[mi][ni], 0, 0, 0);
        }
    };

    LOAD(ha0, hb0, 0);
    LOAD(ha1, hb1, 64);

    #pragma unroll
    for (int m2 = 0; m2 < DIM / 128; m2++) {
        const int k0 = m2 * 128;
        STORE(As[0], Bs[0], ha0, hb0);
        if (k0 + 128 < DIM) LOAD(ha0, hb0, k0 + 128);
        __syncthreads();
        COMPUTE(As[0], Bs[0]);
        STORE(As[1], Bs[1], ha1, hb1);
        if (k0 + 192 < DIM) LOAD(ha1, hb1, k0 + 192);
        __syncthreads();
        COMPUTE(As[1], Bs[1]);
    }
}

// ---------------- QKV projection (also zeroes the out_gemm row-group counters) ----------------
__global__ __launch_bounds__(256) void qkv_gemm(
        const bfraw* __restrict__ Xb, const bfraw* __restrict__ Wb,
        bfraw* __restrict__ Qp, bfraw* __restrict__ Kp, bfraw* __restrict__ Vt,
        int* __restrict__ cnt) {
    if (blockIdx.x == 0 && blockIdx.y == 0 && blockIdx.z == 0 && threadIdx.x < 32)
        cnt[threadIdx.x] = 0;
    const int which = blockIdx.z;
    const bfraw* A = Xb + which * (MROWS * DIM);
    const bfraw* B = Wb + which * (DIM * DIM);
    bfraw* O = (which == 0) ? Qp : (which == 1) ? Kp : Vt;
    const int m0 = blockIdx.x * 128, n0 = blockIdx.y * 128;
    f32x4 acc[4][4];
    gemm128(A, B, m0, n0, acc);
    const int lane = threadIdx.x & 63, wave = threadIdx.x >> 6;
    const int lrow = lane & 15, quad = lane >> 4;
    const int wy = wave >> 1, wx = wave & 1;
    const float scale = (which == 0) ? QSCALE : 1.0f;
    #pragma unroll
    for (int mi = 0; mi < 4; mi++)
        #pragma unroll
        for (int ni = 0; ni < 4; ni++)
            #pragma unroll
            for (int i = 0; i < 4; i++) {
                int m = m0 + wy * 64 + mi * 16 + quad * 4 + i;
                int n = n0 + wx * 64 + ni * 16 + lrow;
                int b = m >> 11, s = m & (SEQ - 1), h = n >> 6, kk = n & (DK - 1);
                bfraw v = f2bf(acc[mi][ni][i] * scale);
                if (which == 2) O[(((b * NH + h) * DK) + kk) * SEQ + s] = v;
                else            O[(((b * NH + h) * SEQ) + s) * DK + kk] = v;
            }
}

// ---------------- flash MFMA attention: 8 waves, 128 q/block, self-computed V prefix ----------------
// vsum kernel fused in: each block sums V[d][s<diagKt] itself (Vt is L2/L3-resident),
// LDS-reduced to Scol[64]; Oa init = PCONST * Scol. Everything else = R6 structure.
template<bool NEAR>
__device__ __forceinline__ void qk_soft(
        const bfraw* Kb, const bf16x8 qf[2], const float* Mkf,
        int kt0, int lrow, int quad, int q_ln, float& lsum, s16x4 pb[4]) {
    #pragma unroll
    for (int n = 0; n < 4; n++) {
        const int srow = n * 16 + lrow;
        bf16x8 kfa = *(const bf16x8*)&Kb[srow * 64 + ((quad ^ (lrow & 7)) << 3)];
        bf16x8 kfb = *(const bf16x8*)&Kb[srow * 64 + (((4 | quad) ^ (lrow & 7)) << 3)];
        f32x4 z = {0.f, 0.f, 0.f, 0.f};
        z = __builtin_amdgcn_mfma_f32_16x16x32_bf16(kfa, qf[0], z, 0, 0, 0);
        z = __builtin_amdgcn_mfma_f32_16x16x32_bf16(kfb, qf[1], z, 0, 0, 0);
        f32x4 mv = *(const f32x4*)&Mkf[kt0 + n * 16 + quad * 4];   // 4 contiguous floats
        union { bf16x4 h; s16x4 s; } pk;
        #pragma unroll
        for (int i = 0; i < 4; i++) {
            float m = mv[i];
            if (NEAR) { int s = kt0 + n * 16 + quad * 4 + i; m = (s > q_ln) ? m : 0.0f; }
            float p = fexp2(fmaf(m, z[i] - SENT, SENT));
            lsum += p;
            pk.h[i] = (__bf16)p;
        }
        pb[n] = pk.s;
    }
}

__global__ __launch_bounds__(512) void attn_flash(
        const bfraw* __restrict__ Qp, const bfraw* __restrict__ Kp, const bfraw* __restrict__ Vt,
        const int* __restrict__ mask, bfraw* __restrict__ Ctx) {
    __shared__ __align__(16) bfraw Ks[2][64 * 64];
    __shared__ __align__(16) bfraw Vs[2][64 * 64];
    __shared__ float Mkf[SEQ];
    __shared__ float Ps[8][64];
    __shared__ float Scol[64];
    const int bh = blockIdx.x, yy = blockIdx.y;
    const int gg = yy >> 3, jj = yy & 7;       // pairs {j, 15-j}: const total work
    const int qt = gg ? (15 - jj) : jj;        // 128-row q tile
    const int b = bh >> 4, h = bh & 15;
    const int tid = threadIdx.x, wave = tid >> 6, lane = tid & 63;
    const int lrow = lane & 15, quad = lane >> 4;
    const int baseK = ((b * NH + h) * SEQ) * DK;
    const int baseV = ((b * NH + h) * DK) * SEQ;
    const int qbase = qt * 128 + wave * 16;
    const int q_ln  = qbase + lrow;            // this lane's q (col of S^T)
    const int diagKt = qt * 128;
    const int ldr = tid >> 3;                  // 512 threads: row 0..63, chunk 0..7
    const int c8  = tid & 7;
    const int ldc = c8 << 3;
    const int cl  = ((c8 ^ (ldr & 7)) << 3);   // swizzled LDS chunk

    // ---- fused V prefix (replaces vsum kernel): Scol[d] = sum_{s<diagKt} V[d][s]
    const int d_v = tid & 63, part = tid >> 6;
    float pacc = 0.f;
    {
        const bfraw* vrow = Vt + baseV + d_v * SEQ;
        for (int s0 = part * 8; s0 < diagKt; s0 += 64) {
            u16x8 v = *(const u16x8*)(vrow + s0);
            #pragma unroll
            for (int e = 0; e < 8; e++) pacc += bf2f(v[e]);
        }
    }
    for (int i = tid; i < SEQ; i += 512) Mkf[i] = (mask[b * SEQ + i] != 0) ? 1.0f : 0.0f;
    Ps[part][d_v] = pacc;
    __syncthreads();
    if (tid < 64) {
        float sc = 0.f;
        #pragma unroll
        for (int p = 0; p < 8; p++) sc += Ps[p][tid];
        Scol[tid] = sc;
    }
    __syncthreads();

    bf16x8 qf[2];                              // B-operand: Q[q=lrow][k=ks*32+quad*8+j]
    qf[0] = *(const bf16x8*)(Qp + baseK + q_ln * DK + quad * 8);
    qf[1] = *(const bf16x8*)(Qp + baseK + q_ln * DK + 32 + quad * 8);

    f32x4 Oa[4];                               // O^T: row=d=nd*16+quad*4+i, col=q
    #pragma unroll
    for (int nd = 0; nd < 4; nd++)
        #pragma unroll
        for (int i = 0; i < 4; i++)
            Oa[nd][i] = PCONST * Scol[nd * 16 + quad * 4 + i];
    float lsum = 0.f;

    const int nt = (SEQ - diagKt) >> 6;        // 32 - 2*qt, even, >= 2
    int kt0 = diagKt;
    u16x8 k0 = *(const u16x8*)(Kp + baseK + (kt0 + ldr) * DK + ldc);
    u16x8 v0 = *(const u16x8*)(Vt + baseV + ldr * SEQ + kt0 + ldc);

    for (int t = 0; t < nt; t++, kt0 += 64) {
        bfraw* Kb = Ks[t & 1];
        bfraw* Vb = Vs[t & 1];
        *(u16x8*)&Kb[ldr * 64 + cl] = k0;
        *(u16x8*)&Vb[ldr * 64 + cl] = v0;
        if (t + 1 < nt) {                      // prefetch overlaps barrier + compute
            const int kn = kt0 + 64;
            k0 = *(const u16x8*)(Kp + baseK + (kn + ldr) * DK + ldc);
            v0 = *(const u16x8*)(Vt + baseV + ldr * SEQ + kn + ldc);
        }
        __syncthreads();                       // single barrier per tile (dbuf)

        s16x4 pb[4];
        if (t < 2) qk_soft<true >(Kb, qf, Mkf, kt0, lrow, quad, q_ln, lsum, pb);
        else       qk_soft<false>(Kb, qf, Mkf, kt0, lrow, quad, q_ln, lsum, pb);

        #pragma unroll
        for (int nd = 0; nd < 4; nd++) {
            const int d = nd * 16 + lrow;
            #pragma unroll
            for (int sc = 0; sc < 4; sc++) {
                s16x4 vf = *(const s16x4*)&Vb[d * 64
                    + ((((sc << 1) | (quad >> 1)) ^ (d & 7)) << 3) + ((quad & 1) << 2)];
                Oa[nd] = mfma16(vf, pb[sc], Oa[nd]);
            }
        }
    }

    float r = lsum;
    r += __shfl_xor(r, 16, 64);
    r += __shfl_xor(r, 32, 64);
    const float inv = 1.0f / (r + (float)diagKt * PCONST);
    #pragma unroll
    for (int nd = 0; nd < 4; nd++) {
        u16x4 o;
        #pragma unroll
        for (int i = 0; i < 4; i++) o[i] = f2bf(Oa[nd][i] * inv);
        *(u16x4*)&Ctx[(b * SEQ + q_ln) * DIM + h * DK + nd * 16 + quad * 4] = o;
    }
}

// ---------------- output projection + fused residual/LayerNorm epilogue ----------------
// Last-arriving block of each 128-row group (device-scope atomic counter, threadfence
// release/acquire) runs LN for the group: wave-per-row, shuffle reduce, no extra launch.
__global__ __launch_bounds__(256) void out_gemm(
        const bfraw* __restrict__ Ctx, const bfraw* __restrict__ WoB,
        const float* __restrict__ Xq, const float* __restrict__ gamma,
        const float* __restrict__ beta, float* __restrict__ C,
        float* __restrict__ out, int* __restrict__ cnt) {
    const int m0 = blockIdx.x * 128, n0 = blockIdx.y * 128;
    f32x4 acc[4][4];
    gemm128(Ctx, WoB, m0, n0, acc);
    const int tid = threadIdx.x;
    const int lane = tid & 63, wave = tid >> 6;
    const int lrow = lane & 15, quad = lane >> 4;
    const int wy = wave >> 1, wx = wave & 1;
    #pragma unroll
    for (int mi = 0; mi < 4; mi++)
        #pragma unroll
        for (int ni = 0; ni < 4; ni++)
            #pragma unroll
            for (int i = 0; i < 4; i++) {
                int m = m0 + wy * 64 + mi * 16 + quad * 4 + i;
                int n = n0 + wx * 64 + ni * 16 + lrow;
                C[m * DIM + n] = acc[mi][ni][i];
            }
    __threadfence();                            // release C-tile writes (device scope)
    __syncthreads();
    __shared__ int lastblk;
    if (tid == 0) lastblk = (atomicAdd(&cnt[blockIdx.x], 1) == 7);
    __syncthreads();
    if (!lastblk) return;
    __threadfence();                            // acquire: see all 8 tiles of this row group

    // LN rows [m0, m0+128): wave w handles rows m0 + w + 4r
    f32x4 g[4], bt[4];
    #pragma unroll
    for (int jj = 0; jj < 4; jj++) {
        g[jj]  = *(const f32x4*)&gamma[lane * 16 + jj * 4];
        bt[jj] = *(const f32x4*)&beta [lane * 16 + jj * 4];
    }
    for (int r = 0; r < 32; r++) {
        const int row = m0 + wave + (r << 2);
        const float* crow = C  + row * DIM + lane * 16;
        const float* xrow = Xq + row * DIM + lane * 16;
        f32x4 v[4]; float s = 0.f, s2 = 0.f;
        #pragma unroll
        for (int jj = 0; jj < 4; jj++) {
            f32x4 cv = *(const f32x4*)(crow + jj * 4);
            f32x4 xv = *(const f32x4*)(xrow + jj * 4);
            #pragma unroll
            for (int e = 0; e < 4; e++) {
                float x = cv[e] + xv[e];
                v[jj][e] = x; s += x; s2 += x * x;
            }
        }
        #pragma unroll
        for (int off = 1; off < 64; off <<= 1) {
            s  += __shfl_xor(s,  off, 64);
            s2 += __shfl_xor(s2, off, 64);
        }
        float mu   = s * (1.0f / DIM);
        float var  = s2 * (1.0f / DIM) - mu * mu;
        float rstd = rsqrtf(var + 1e-5f);
        float* orow = out + row * DIM + lane * 16;
        #pragma unroll
        for (int jj = 0; jj < 4; jj++) {
            f32x4 o;
            #pragma unroll
            for (int e = 0; e < 4; e++) o[e] = (v[jj][e] - mu) * rstd * g[jj][e] + bt[jj][e];
            *(f32x4*)(orow + jj * 4) = o;
        }
    }
}

extern "C" void kernel_launch(void* const* d_in, const int* in_sizes, int n_in,
                              void* d_out, int out_size, void* d_ws, size_t ws_size,
                              hipStream_t stream) {
    const float* Xq    = (const float*)d_in[0];
    const float* Xk    = (const float*)d_in[1];
    const float* Xv    = (const float*)d_in[2];
    const int*   mask  = (const int*)  d_in[3];
    const float* Wq    = (const float*)d_in[4];
    const float* Wk    = (const float*)d_in[5];
    const float* Wv    = (const float*)d_in[6];
    const float* Wo    = (const float*)d_in[7];
    const float* gamma = (const float*)d_in[8];
    const float* beta  = (const float*)d_in[9];
    float* out = (float*)d_out;

    char* ws = (char*)d_ws;
    bfraw* Xb   = (bfraw*)(ws);                 // [0,24MB) dead after qkv
    bfraw* Wb   = (bfraw*)(ws + (24u << 20));
    bfraw* Qp   = (bfraw*)(ws + (32u << 20));
    bfraw* Kp   = (bfraw*)(ws + (40u << 20));
    bfraw* Vt   = (bfraw*)(ws + (48u << 20));
    bfraw* Ctx  = (bfraw*)(ws + (56u << 20));
    float* C    = (float*)(ws);                 // [0,16MB) reuses dead Xb
    int*   cnt  = (int*)(ws + (16u << 20));     // untouched after cvt; zeroed by qkv blk0

    dim3 blk(256);
    cvt_kernel<<<dim3(MROWS * DIM / (256 * 8), 7), blk, 0, stream>>>(Xq, Xk, Xv, Wq, Wk, Wv, Wo, Xb, Wb);
    qkv_gemm  <<<dim3(MROWS / 128, DIM / 128, 3),  blk, 0, stream>>>(Xb, Wb, Qp, Kp, Vt, cnt);
    attn_flash<<<dim3(BATCH * NH, SEQ / 128),      dim3(512), 0, stream>>>(Qp, Kp, Vt, mask, Ctx);
    out_gemm  <<<dim3(MROWS / 128, DIM / 128),     blk, 0, stream>>>(Ctx, Wb + 3 * (DIM * DIM), Xq, gamma, beta, C, out, cnt);
}

// Round 9
// 214.147 us; speedup vs baseline: 1.2713x; 1.2713x over previous
//
#include <hip/hip_runtime.h>

#define NH    16
#define DK    64
#define DIM   1024
#define BATCH 2
#define SEQ   2048
#define MROWS (BATCH*SEQ)   // 4096
#define QSCALE 0.18033688011112043f   // 0.125 * log2(e): folded into Q projection
#define SENT   -44.0f                 // sentinel in log2 domain; exp2(-44)=5.68e-14
#define PCONST 5.684341886080802e-14f // exp2(-44)

typedef unsigned short bfraw;
typedef __attribute__((ext_vector_type(8))) __bf16 bf16x8;
typedef __attribute__((ext_vector_type(4))) __bf16 bf16x4;
typedef __attribute__((ext_vector_type(8))) unsigned short u16x8;
typedef __attribute__((ext_vector_type(4))) unsigned short u16x4;
typedef __attribute__((ext_vector_type(4))) short s16x4;
typedef __attribute__((ext_vector_type(4))) float f32x4;

__device__ __forceinline__ float bf2f(bfraw u) {
    union { unsigned int i; float f; } x; x.i = ((unsigned int)u) << 16; return x.f;
}
__device__ __forceinline__ bfraw f2bf(float f) {          // RNE
    union { float f; unsigned int i; } x; x.f = f;
    unsigned int r = x.i + 0x7FFFu + ((x.i >> 16) & 1u);
    return (bfraw)(r >> 16);
}
__device__ __forceinline__ float fexp2(float x) {
#if __has_builtin(__builtin_amdgcn_exp2f)
    return __builtin_amdgcn_exp2f(x);
#else
    return exp2f(x);
#endif
}

// K=16 bf16 MFMA: D = A(16x16) * B(16x16) + C.
__device__ __forceinline__ f32x4 mfma16(s16x4 a, s16x4 b, f32x4 c) {
#if __has_builtin(__builtin_amdgcn_mfma_f32_16x16x16_bf16)
    union { s16x4 s; bf16x4 h; } ua, ub; ua.s = a; ub.s = b;
    return __builtin_amdgcn_mfma_f32_16x16x16_bf16(ua.h, ub.h, c, 0, 0, 0);
#elif __has_builtin(__builtin_amdgcn_mfma_f32_16x16x16bf16_1k)
    return __builtin_amdgcn_mfma_f32_16x16x16bf16_1k(a, b, c, 0, 0, 0);
#else
    asm("v_mfma_f32_16x16x16_bf16 %0, %1, %2, %0" : "+v"(c) : "v"(a), "v"(b));
    return c;
#endif
}

__device__ __forceinline__ float block_reduce(float val, float* rbuf, int op) {
    const int lane = threadIdx.x & 63, wave = threadIdx.x >> 6;
    #pragma unroll
    for (int off = 32; off; off >>= 1) {
        float o = __shfl_xor(val, off, 64);
        val = op ? (val + o) : fmaxf(val, o);
    }
    if (lane == 0) rbuf[wave] = val;
    __syncthreads();
    float r = op ? (rbuf[0] + rbuf[1] + rbuf[2] + rbuf[3])
                 : fmaxf(fmaxf(rbuf[0], rbuf[1]), fmaxf(rbuf[2], rbuf[3]));
    __syncthreads();
    return r;
}

// ---------------- fp32 -> bf16 convert pass ----------------
__global__ __launch_bounds__(256) void cvt_kernel(
        const float* __restrict__ x0, const float* __restrict__ x1, const float* __restrict__ x2,
        const float* __restrict__ w0, const float* __restrict__ w1, const float* __restrict__ w2,
        const float* __restrict__ w3, bfraw* __restrict__ Xb, bfraw* __restrict__ Wb) {
    const int t = blockIdx.y;
    const float* src; bfraw* dst; int n;
    if (t < 3) { src = (t == 0) ? x0 : (t == 1) ? x1 : x2; dst = Xb + t * (MROWS * DIM); n = MROWS * DIM; }
    else { int u = t - 3; src = (u == 0) ? w0 : (u == 1) ? w1 : (u == 2) ? w2 : w3;
           dst = Wb + u * (DIM * DIM); n = DIM * DIM; }
    int idx = (blockIdx.x * 256 + threadIdx.x) * 8;
    if (idx >= n) return;
    f32x4 a = *(const f32x4*)(src + idx);
    f32x4 b = *(const f32x4*)(src + idx + 4);
    u16x8 o;
    #pragma unroll
    for (int j = 0; j < 4; j++) { o[j] = f2bf(a[j]); o[4 + j] = f2bf(b[j]); }
    *(u16x8*)(dst + idx) = o;
}

// ---------------- 128x128 MFMA GEMM, BK=64 ----------------
// Double-buffered LDS (ONE barrier per K-step) + 2-deep register prefetch.
__device__ __forceinline__ void gemm128(const bfraw* __restrict__ A, const bfraw* __restrict__ B,
                                        int m0, int n0, f32x4 acc[4][4]) {
    __shared__ __align__(16) bfraw As[2][128 * 64];
    __shared__ __align__(16) bfraw Bs[2][128 * 64];
    const int tid = threadIdx.x, wave = tid >> 6;
    const int lane = tid & 63, lrow = lane & 15, quad = lane >> 4;
    const int wy = wave >> 1, wx = wave & 1;
    const int swz = lrow & 7;
    const int srow = tid >> 2;
    const int cg0  = (tid & 3) << 1;
    const int gc   = cg0 << 3;
    const int e7   = srow & 7;
    const int o0 = ((cg0 ^ e7) << 3), o1 = (((cg0 | 1) ^ e7) << 3);

    const bfraw* pa0 = A + (m0 + srow) * DIM + gc;
    const bfraw* pa1 = A + (m0 + 64 + srow) * DIM + gc;
    const bfraw* pb0 = B + (n0 + srow) * DIM + gc;
    const bfraw* pb1 = B + (n0 + 64 + srow) * DIM + gc;

    #pragma unroll
    for (int i = 0; i < 4; i++)
        #pragma unroll
        for (int j = 0; j < 4; j++) { f32x4 z = {0.f, 0.f, 0.f, 0.f}; acc[i][j] = z; }

    u16x8 ha0[4], hb0[4], ha1[4], hb1[4];

    auto LOAD = [&](u16x8 ha[4], u16x8 hb[4], int kk) {
        ha[0] = *(const u16x8*)(pa0 + kk);     ha[1] = *(const u16x8*)(pa0 + kk + 8);
        ha[2] = *(const u16x8*)(pa1 + kk);     ha[3] = *(const u16x8*)(pa1 + kk + 8);
        hb[0] = *(const u16x8*)(pb0 + kk);     hb[1] = *(const u16x8*)(pb0 + kk + 8);
        hb[2] = *(const u16x8*)(pb1 + kk);     hb[3] = *(const u16x8*)(pb1 + kk + 8);
    };
    auto STORE = [&](bfraw* Ad, bfraw* Bd, u16x8 ha[4], u16x8 hb[4]) {
        *(u16x8*)&Ad[srow * 64 + o0]        = ha[0];
        *(u16x8*)&Ad[srow * 64 + o1]        = ha[1];
        *(u16x8*)&Ad[(64 + srow) * 64 + o0] = ha[2];
        *(u16x8*)&Ad[(64 + srow) * 64 + o1] = ha[3];
        *(u16x8*)&Bd[srow * 64 + o0]        = hb[0];
        *(u16x8*)&Bd[srow * 64 + o1]        = hb[1];
        *(u16x8*)&Bd[(64 + srow) * 64 + o0] = hb[2];
        *(u16x8*)&Bd[(64 + srow) * 64 + o1] = hb[3];
    };
    auto COMPUTE = [&](const bfraw* Ad, const bfraw* Bd) {
        #pragma unroll
        for (int ks = 0; ks < 2; ks++) {
            const int c = (ks << 2) | quad;
            bf16x8 af[4], bfg[4];
            #pragma unroll
            for (int mi = 0; mi < 4; mi++)
                af[mi] = *(const bf16x8*)&Ad[(wy * 64 + mi * 16 + lrow) * 64 + ((c ^ swz) << 3)];
            #pragma unroll
            for (int ni = 0; ni < 4; ni++)
                bfg[ni] = *(const bf16x8*)&Bd[(wx * 64 + ni * 16 + lrow) * 64 + ((c ^ swz) << 3)];
            #pragma unroll
            for (int mi = 0; mi < 4; mi++)
                #pragma unroll
                for (int ni = 0; ni < 4; ni++)
                    acc[mi][ni] = __builtin_amdgcn_mfma_f32_16x16x32_bf16(af[mi], bfg[ni], acc[mi][ni], 0, 0, 0);
        }
    };

    LOAD(ha0, hb0, 0);
    LOAD(ha1, hb1, 64);

    #pragma unroll
    for (int m2 = 0; m2 < DIM / 128; m2++) {
        const int k0 = m2 * 128;
        STORE(As[0], Bs[0], ha0, hb0);
        if (k0 + 128 < DIM) LOAD(ha0, hb0, k0 + 128);
        __syncthreads();
        COMPUTE(As[0], Bs[0]);
        STORE(As[1], Bs[1], ha1, hb1);
        if (k0 + 192 < DIM) LOAD(ha1, hb1, k0 + 192);
        __syncthreads();
        COMPUTE(As[1], Bs[1]);
    }
}

// ---------------- QKV projection ----------------
__global__ __launch_bounds__(256) void qkv_gemm(
        const bfraw* __restrict__ Xb, const bfraw* __restrict__ Wb,
        bfraw* __restrict__ Qp, bfraw* __restrict__ Kp, bfraw* __restrict__ Vt) {
    const int which = blockIdx.z;
    const bfraw* A = Xb + which * (MROWS * DIM);
    const bfraw* B = Wb + which * (DIM * DIM);
    bfraw* O = (which == 0) ? Qp : (which == 1) ? Kp : Vt;
    const int m0 = blockIdx.x * 128, n0 = blockIdx.y * 128;
    f32x4 acc[4][4];
    gemm128(A, B, m0, n0, acc);
    const int lane = threadIdx.x & 63, wave = threadIdx.x >> 6;
    const int lrow = lane & 15, quad = lane >> 4;
    const int wy = wave >> 1, wx = wave & 1;
    const float scale = (which == 0) ? QSCALE : 1.0f;
    #pragma unroll
    for (int mi = 0; mi < 4; mi++)
        #pragma unroll
        for (int ni = 0; ni < 4; ni++)
            #pragma unroll
            for (int i = 0; i < 4; i++) {
                int m = m0 + wy * 64 + mi * 16 + quad * 4 + i;
                int n = n0 + wx * 64 + ni * 16 + lrow;
                int b = m >> 11, s = m & (SEQ - 1), h = n >> 6, kk = n & (DK - 1);
                bfraw v = f2bf(acc[mi][ni][i] * scale);
                if (which == 2) O[(((b * NH + h) * DK) + kk) * SEQ + s] = v;
                else            O[(((b * NH + h) * SEQ) + s) * DK + kk] = v;
            }
}

// ---------------- flash MFMA attention: 8 waves, 128 q/block, self-computed V prefix ----------------
// vsum kernel fused in: each block sums V[d][s<diagKt] itself (Vt is L2/L3-resident),
// LDS-reduced to Scol[64]; Oa init = PCONST * Scol. Verified passing in R8.
template<bool NEAR>
__device__ __forceinline__ void qk_soft(
        const bfraw* Kb, const bf16x8 qf[2], const float* Mkf,
        int kt0, int lrow, int quad, int q_ln, float& lsum, s16x4 pb[4]) {
    #pragma unroll
    for (int n = 0; n < 4; n++) {
        const int srow = n * 16 + lrow;
        bf16x8 kfa = *(const bf16x8*)&Kb[srow * 64 + ((quad ^ (lrow & 7)) << 3)];
        bf16x8 kfb = *(const bf16x8*)&Kb[srow * 64 + (((4 | quad) ^ (lrow & 7)) << 3)];
        f32x4 z = {0.f, 0.f, 0.f, 0.f};
        z = __builtin_amdgcn_mfma_f32_16x16x32_bf16(kfa, qf[0], z, 0, 0, 0);
        z = __builtin_amdgcn_mfma_f32_16x16x32_bf16(kfb, qf[1], z, 0, 0, 0);
        f32x4 mv = *(const f32x4*)&Mkf[kt0 + n * 16 + quad * 4];   // 4 contiguous floats
        union { bf16x4 h; s16x4 s; } pk;
        #pragma unroll
        for (int i = 0; i < 4; i++) {
            float m = mv[i];
            if (NEAR) { int s = kt0 + n * 16 + quad * 4 + i; m = (s > q_ln) ? m : 0.0f; }
            float p = fexp2(fmaf(m, z[i] - SENT, SENT));
            lsum += p;
            pk.h[i] = (__bf16)p;
        }
        pb[n] = pk.s;
    }
}

__global__ __launch_bounds__(512) void attn_flash(
        const bfraw* __restrict__ Qp, const bfraw* __restrict__ Kp, const bfraw* __restrict__ Vt,
        const int* __restrict__ mask, bfraw* __restrict__ Ctx) {
    __shared__ __align__(16) bfraw Ks[2][64 * 64];
    __shared__ __align__(16) bfraw Vs[2][64 * 64];
    __shared__ float Mkf[SEQ];
    __shared__ float Ps[8][64];
    __shared__ float Scol[64];
    const int bh = blockIdx.x, yy = blockIdx.y;
    const int gg = yy >> 3, jj = yy & 7;       // pairs {j, 15-j}: const total work
    const int qt = gg ? (15 - jj) : jj;        // 128-row q tile
    const int b = bh >> 4, h = bh & 15;
    const int tid = threadIdx.x, wave = tid >> 6, lane = tid & 63;
    const int lrow = lane & 15, quad = lane >> 4;
    const int baseK = ((b * NH + h) * SEQ) * DK;
    const int baseV = ((b * NH + h) * DK) * SEQ;
    const int qbase = qt * 128 + wave * 16;
    const int q_ln  = qbase + lrow;            // this lane's q (col of S^T)
    const int diagKt = qt * 128;
    const int ldr = tid >> 3;                  // 512 threads: row 0..63, chunk 0..7
    const int c8  = tid & 7;
    const int ldc = c8 << 3;
    const int cl  = ((c8 ^ (ldr & 7)) << 3);   // swizzled LDS chunk

    // ---- fused V prefix (replaces vsum kernel): Scol[d] = sum_{s<diagKt} V[d][s]
    const int d_v = tid & 63, part = tid >> 6;
    float pacc = 0.f;
    {
        const bfraw* vrow = Vt + baseV + d_v * SEQ;
        for (int s0 = part * 8; s0 < diagKt; s0 += 64) {
            u16x8 v = *(const u16x8*)(vrow + s0);
            #pragma unroll
            for (int e = 0; e < 8; e++) pacc += bf2f(v[e]);
        }
    }
    for (int i = tid; i < SEQ; i += 512) Mkf[i] = (mask[b * SEQ + i] != 0) ? 1.0f : 0.0f;
    Ps[part][d_v] = pacc;
    __syncthreads();
    if (tid < 64) {
        float sc = 0.f;
        #pragma unroll
        for (int p = 0; p < 8; p++) sc += Ps[p][tid];
        Scol[tid] = sc;
    }
    __syncthreads();

    bf16x8 qf[2];                              // B-operand: Q[q=lrow][k=ks*32+quad*8+j]
    qf[0] = *(const bf16x8*)(Qp + baseK + q_ln * DK + quad * 8);
    qf[1] = *(const bf16x8*)(Qp + baseK + q_ln * DK + 32 + quad * 8);

    f32x4 Oa[4];                               // O^T: row=d=nd*16+quad*4+i, col=q
    #pragma unroll
    for (int nd = 0; nd < 4; nd++)
        #pragma unroll
        for (int i = 0; i < 4; i++)
            Oa[nd][i] = PCONST * Scol[nd * 16 + quad * 4 + i];
    float lsum = 0.f;

    const int nt = (SEQ - diagKt) >> 6;        // 32 - 2*qt, even, >= 2
    int kt0 = diagKt;
    u16x8 k0 = *(const u16x8*)(Kp + baseK + (kt0 + ldr) * DK + ldc);
    u16x8 v0 = *(const u16x8*)(Vt + baseV + ldr * SEQ + kt0 + ldc);

    for (int t = 0; t < nt; t++, kt0 += 64) {
        bfraw* Kb = Ks[t & 1];
        bfraw* Vb = Vs[t & 1];
        *(u16x8*)&Kb[ldr * 64 + cl] = k0;
        *(u16x8*)&Vb[ldr * 64 + cl] = v0;
        if (t + 1 < nt) {                      // prefetch overlaps barrier + compute
            const int kn = kt0 + 64;
            k0 = *(const u16x8*)(Kp + baseK + (kn + ldr) * DK + ldc);
            v0 = *(const u16x8*)(Vt + baseV + ldr * SEQ + kn + ldc);
        }
        __syncthreads();                       // single barrier per tile (dbuf)

        s16x4 pb[4];
        if (t < 2) qk_soft<true >(Kb, qf, Mkf, kt0, lrow, quad, q_ln, lsum, pb);
        else       qk_soft<false>(Kb, qf, Mkf, kt0, lrow, quad, q_ln, lsum, pb);

        #pragma unroll
        for (int nd = 0; nd < 4; nd++) {
            const int d = nd * 16 + lrow;
            #pragma unroll
            for (int sc = 0; sc < 4; sc++) {
                s16x4 vf = *(const s16x4*)&Vb[d * 64
                    + ((((sc << 1) | (quad >> 1)) ^ (d & 7)) << 3) + ((quad & 1) << 2)];
                Oa[nd] = mfma16(vf, pb[sc], Oa[nd]);
            }
        }
    }

    float r = lsum;
    r += __shfl_xor(r, 16, 64);
    r += __shfl_xor(r, 32, 64);
    const float inv = 1.0f / (r + (float)diagKt * PCONST);
    #pragma unroll
    for (int nd = 0; nd < 4; nd++) {
        u16x4 o;
        #pragma unroll
        for (int i = 0; i < 4; i++) o[i] = f2bf(Oa[nd][i] * inv);
        *(u16x4*)&Ctx[(b * SEQ + q_ln) * DIM + h * DK + nd * 16 + quad * 4] = o;
    }
}

// ---------------- output projection ----------------
__global__ __launch_bounds__(256) void out_gemm(
        const bfraw* __restrict__ Ctx, const bfraw* __restrict__ WoB, float* __restrict__ C) {
    const int m0 = blockIdx.x * 128, n0 = blockIdx.y * 128;
    f32x4 acc[4][4];
    gemm128(Ctx, WoB, m0, n0, acc);
    const int lane = threadIdx.x & 63, wave = threadIdx.x >> 6;
    const int lrow = lane & 15, quad = lane >> 4;
    const int wy = wave >> 1, wx = wave & 1;
    #pragma unroll
    for (int mi = 0; mi < 4; mi++)
        #pragma unroll
        for (int ni = 0; ni < 4; ni++)
            #pragma unroll
            for (int i = 0; i < 4; i++) {
                int m = m0 + wy * 64 + mi * 16 + quad * 4 + i;
                int n = n0 + wx * 64 + ni * 16 + lrow;
                C[m * DIM + n] = acc[mi][ni][i];
            }
}

// ---------------- residual + LayerNorm (fp32) ----------------
__global__ __launch_bounds__(256) void ln_kernel(
        const float* __restrict__ C, const float* __restrict__ Xq,
        const float* __restrict__ gamma, const float* __restrict__ beta,
        float* __restrict__ out) {
    __shared__ float rbuf[4];
    const int m = blockIdx.x, tid = threadIdx.x;
    const float* crow = C + m * DIM;
    const float* xrow = Xq + m * DIM;
    float v[4]; float s = 0.f, s2 = 0.f;
    #pragma unroll
    for (int i = 0; i < 4; i++) {
        int d = tid + (i << 8);
        float x = crow[d] + xrow[d];
        v[i] = x; s += x; s2 += x * x;
    }
    float S  = block_reduce(s,  rbuf, 1);
    float S2 = block_reduce(s2, rbuf, 1);
    float mu  = S * (1.0f / DIM);
    float var = S2 * (1.0f / DIM) - mu * mu;
    float rstd = rsqrtf(var + 1e-5f);
    #pragma unroll
    for (int i = 0; i < 4; i++) {
        int d = tid + (i << 8);
        out[m * DIM + d] = (v[i] - mu) * rstd * gamma[d] + beta[d];
    }
}

extern "C" void kernel_launch(void* const* d_in, const int* in_sizes, int n_in,
                              void* d_out, int out_size, void* d_ws, size_t ws_size,
                              hipStream_t stream) {
    const float* Xq    = (const float*)d_in[0];
    const float* Xk    = (const float*)d_in[1];
    const float* Xv    = (const float*)d_in[2];
    const int*   mask  = (const int*)  d_in[3];
    const float* Wq    = (const float*)d_in[4];
    const float* Wk    = (const float*)d_in[5];
    const float* Wv    = (const float*)d_in[6];
    const float* Wo    = (const float*)d_in[7];
    const float* gamma = (const float*)d_in[8];
    const float* beta  = (const float*)d_in[9];
    float* out = (float*)d_out;

    char* ws = (char*)d_ws;
    bfraw* Xb   = (bfraw*)(ws);                 // [0,24MB) dead after qkv
    bfraw* Wb   = (bfraw*)(ws + (24u << 20));
    bfraw* Qp   = (bfraw*)(ws + (32u << 20));
    bfraw* Kp   = (bfraw*)(ws + (40u << 20));
    bfraw* Vt   = (bfraw*)(ws + (48u << 20));
    bfraw* Ctx  = (bfraw*)(ws + (56u << 20));
    float* C    = (float*)(ws);                 // [0,16MB) reuses dead Xb

    dim3 blk(256);
    cvt_kernel<<<dim3(MROWS * DIM / (256 * 8), 7), blk, 0, stream>>>(Xq, Xk, Xv, Wq, Wk, Wv, Wo, Xb, Wb);
    qkv_gemm  <<<dim3(MROWS / 128, DIM / 128, 3),  blk, 0, stream>>>(Xb, Wb, Qp, Kp, Vt);
    attn_flash<<<dim3(BATCH * NH, SEQ / 128),      dim3(512), 0, stream>>>(Qp, Kp, Vt, mask, Ctx);
    out_gemm  <<<dim3(MROWS / 128, DIM / 128),     blk, 0, stream>>>(Ctx, Wb + 3 * (DIM * DIM), C);
    ln_kernel <<<dim3(MROWS),                      blk, 0, stream>>>(C, Xq, gamma, beta, out);
}

// Round 10
// 212.246 us; speedup vs baseline: 1.2827x; 1.0090x over previous
//
#include <hip/hip_runtime.h>

#define NH    16
#define DK    64
#define DIM   1024
#define BATCH 2
#define SEQ   2048
#define MROWS (BATCH*SEQ)   // 4096
#define QSCALE 0.18033688011112043f   // 0.125 * log2(e): folded into Q projection
#define SENT   -44.0f                 // sentinel in log2 domain; exp2(-44)=5.68e-14
#define PCONST 5.684341886080802e-14f // exp2(-44)

typedef unsigned short bfraw;
typedef __attribute__((ext_vector_type(8))) __bf16 bf16x8;
typedef __attribute__((ext_vector_type(4))) __bf16 bf16x4;
typedef __attribute__((ext_vector_type(8))) unsigned short u16x8;
typedef __attribute__((ext_vector_type(4))) unsigned short u16x4;
typedef __attribute__((ext_vector_type(4))) short s16x4;
typedef __attribute__((ext_vector_type(4))) float f32x4;

__device__ __forceinline__ float bf2f(bfraw u) {
    union { unsigned int i; float f; } x; x.i = ((unsigned int)u) << 16; return x.f;
}
__device__ __forceinline__ bfraw f2bf(float f) {          // RNE
    union { float f; unsigned int i; } x; x.f = f;
    unsigned int r = x.i + 0x7FFFu + ((x.i >> 16) & 1u);
    return (bfraw)(r >> 16);
}
__device__ __forceinline__ float fexp2(float x) {
#if __has_builtin(__builtin_amdgcn_exp2f)
    return __builtin_amdgcn_exp2f(x);
#else
    return exp2f(x);
#endif
}

// K=16 bf16 MFMA: D = A(16x16) * B(16x16) + C.
__device__ __forceinline__ f32x4 mfma16(s16x4 a, s16x4 b, f32x4 c) {
#if __has_builtin(__builtin_amdgcn_mfma_f32_16x16x16_bf16)
    union { s16x4 s; bf16x4 h; } ua, ub; ua.s = a; ub.s = b;
    return __builtin_amdgcn_mfma_f32_16x16x16_bf16(ua.h, ub.h, c, 0, 0, 0);
#elif __has_builtin(__builtin_amdgcn_mfma_f32_16x16x16bf16_1k)
    return __builtin_amdgcn_mfma_f32_16x16x16bf16_1k(a, b, c, 0, 0, 0);
#else
    asm("v_mfma_f32_16x16x16_bf16 %0, %1, %2, %0" : "+v"(c) : "v"(a), "v"(b));
    return c;
#endif
}

__device__ __forceinline__ float block_reduce(float val, float* rbuf, int op) {
    const int lane = threadIdx.x & 63, wave = threadIdx.x >> 6;
    #pragma unroll
    for (int off = 32; off; off >>= 1) {
        float o = __shfl_xor(val, off, 64);
        val = op ? (val + o) : fmaxf(val, o);
    }
    if (lane == 0) rbuf[wave] = val;
    __syncthreads();
    float r = op ? (rbuf[0] + rbuf[1] + rbuf[2] + rbuf[3])
                 : fmaxf(fmaxf(rbuf[0], rbuf[1]), fmaxf(rbuf[2], rbuf[3]));
    __syncthreads();
    return r;
}

// ---------------- fp32 -> bf16 convert pass ----------------
__global__ __launch_bounds__(256) void cvt_kernel(
        const float* __restrict__ x0, const float* __restrict__ x1, const float* __restrict__ x2,
        const float* __restrict__ w0, const float* __restrict__ w1, const float* __restrict__ w2,
        const float* __restrict__ w3, bfraw* __restrict__ Xb, bfraw* __restrict__ Wb) {
    const int t = blockIdx.y;
    const float* src; bfraw* dst; int n;
    if (t < 3) { src = (t == 0) ? x0 : (t == 1) ? x1 : x2; dst = Xb + t * (MROWS * DIM); n = MROWS * DIM; }
    else { int u = t - 3; src = (u == 0) ? w0 : (u == 1) ? w1 : (u == 2) ? w2 : w3;
           dst = Wb + u * (DIM * DIM); n = DIM * DIM; }
    int idx = (blockIdx.x * 256 + threadIdx.x) * 8;
    if (idx >= n) return;
    f32x4 a = *(const f32x4*)(src + idx);
    f32x4 b = *(const f32x4*)(src + idx + 4);
    u16x8 o;
    #pragma unroll
    for (int j = 0; j < 4; j++) { o[j] = f2bf(a[j]); o[4 + j] = f2bf(b[j]); }
    *(u16x8*)(dst + idx) = o;
}

// ---------------- 128x128 MFMA GEMM, BK=64 ----------------
// Double-buffered LDS (ONE barrier per K-step) + 2-deep register prefetch.
__device__ __forceinline__ void gemm128(const bfraw* __restrict__ A, const bfraw* __restrict__ B,
                                        int m0, int n0, f32x4 acc[4][4]) {
    __shared__ __align__(16) bfraw As[2][128 * 64];
    __shared__ __align__(16) bfraw Bs[2][128 * 64];
    const int tid = threadIdx.x, wave = tid >> 6;
    const int lane = tid & 63, lrow = lane & 15, quad = lane >> 4;
    const int wy = wave >> 1, wx = wave & 1;
    const int swz = lrow & 7;
    const int srow = tid >> 2;
    const int cg0  = (tid & 3) << 1;
    const int gc   = cg0 << 3;
    const int e7   = srow & 7;
    const int o0 = ((cg0 ^ e7) << 3), o1 = (((cg0 | 1) ^ e7) << 3);

    const bfraw* pa0 = A + (m0 + srow) * DIM + gc;
    const bfraw* pa1 = A + (m0 + 64 + srow) * DIM + gc;
    const bfraw* pb0 = B + (n0 + srow) * DIM + gc;
    const bfraw* pb1 = B + (n0 + 64 + srow) * DIM + gc;

    #pragma unroll
    for (int i = 0; i < 4; i++)
        #pragma unroll
        for (int j = 0; j < 4; j++) { f32x4 z = {0.f, 0.f, 0.f, 0.f}; acc[i][j] = z; }

    u16x8 ha0[4], hb0[4], ha1[4], hb1[4];

    auto LOAD = [&](u16x8 ha[4], u16x8 hb[4], int kk) {
        ha[0] = *(const u16x8*)(pa0 + kk);     ha[1] = *(const u16x8*)(pa0 + kk + 8);
        ha[2] = *(const u16x8*)(pa1 + kk);     ha[3] = *(const u16x8*)(pa1 + kk + 8);
        hb[0] = *(const u16x8*)(pb0 + kk);     hb[1] = *(const u16x8*)(pb0 + kk + 8);
        hb[2] = *(const u16x8*)(pb1 + kk);     hb[3] = *(const u16x8*)(pb1 + kk + 8);
    };
    auto STORE = [&](bfraw* Ad, bfraw* Bd, u16x8 ha[4], u16x8 hb[4]) {
        *(u16x8*)&Ad[srow * 64 + o0]        = ha[0];
        *(u16x8*)&Ad[srow * 64 + o1]        = ha[1];
        *(u16x8*)&Ad[(64 + srow) * 64 + o0] = ha[2];
        *(u16x8*)&Ad[(64 + srow) * 64 + o1] = ha[3];
        *(u16x8*)&Bd[srow * 64 + o0]        = hb[0];
        *(u16x8*)&Bd[srow * 64 + o1]        = hb[1];
        *(u16x8*)&Bd[(64 + srow) * 64 + o0] = hb[2];
        *(u16x8*)&Bd[(64 + srow) * 64 + o1] = hb[3];
    };
    auto COMPUTE = [&](const bfraw* Ad, const bfraw* Bd) {
        #pragma unroll
        for (int ks = 0; ks < 2; ks++) {
            const int c = (ks << 2) | quad;
            bf16x8 af[4], bfg[4];
            #pragma unroll
            for (int mi = 0; mi < 4; mi++)
                af[mi] = *(const bf16x8*)&Ad[(wy * 64 + mi * 16 + lrow) * 64 + ((c ^ swz) << 3)];
            #pragma unroll
            for (int ni = 0; ni < 4; ni++)
                bfg[ni] = *(const bf16x8*)&Bd[(wx * 64 + ni * 16 + lrow) * 64 + ((c ^ swz) << 3)];
            #pragma unroll
            for (int mi = 0; mi < 4; mi++)
                #pragma unroll
                for (int ni = 0; ni < 4; ni++)
                    acc[mi][ni] = __builtin_amdgcn_mfma_f32_16x16x32_bf16(af[mi], bfg[ni], acc[mi][ni], 0, 0, 0);
        }
    };

    LOAD(ha0, hb0, 0);
    LOAD(ha1, hb1, 64);

    #pragma unroll
    for (int m2 = 0; m2 < DIM / 128; m2++) {
        const int k0 = m2 * 128;
        STORE(As[0], Bs[0], ha0, hb0);
        if (k0 + 128 < DIM) LOAD(ha0, hb0, k0 + 128);
        __syncthreads();
        COMPUTE(As[0], Bs[0]);
        STORE(As[1], Bs[1], ha1, hb1);
        if (k0 + 192 < DIM) LOAD(ha1, hb1, k0 + 192);
        __syncthreads();
        COMPUTE(As[1], Bs[1]);
    }
}

// ---------------- QKV projection ----------------
__global__ __launch_bounds__(256) void qkv_gemm(
        const bfraw* __restrict__ Xb, const bfraw* __restrict__ Wb,
        bfraw* __restrict__ Qp, bfraw* __restrict__ Kp, bfraw* __restrict__ Vt) {
    const int which = blockIdx.z;
    const bfraw* A = Xb + which * (MROWS * DIM);
    const bfraw* B = Wb + which * (DIM * DIM);
    bfraw* O = (which == 0) ? Qp : (which == 1) ? Kp : Vt;
    const int m0 = blockIdx.x * 128, n0 = blockIdx.y * 128;
    f32x4 acc[4][4];
    gemm128(A, B, m0, n0, acc);
    const int lane = threadIdx.x & 63, wave = threadIdx.x >> 6;
    const int lrow = lane & 15, quad = lane >> 4;
    const int wy = wave >> 1, wx = wave & 1;
    const float scale = (which == 0) ? QSCALE : 1.0f;
    #pragma unroll
    for (int mi = 0; mi < 4; mi++)
        #pragma unroll
        for (int ni = 0; ni < 4; ni++)
            #pragma unroll
            for (int i = 0; i < 4; i++) {
                int m = m0 + wy * 64 + mi * 16 + quad * 4 + i;
                int n = n0 + wx * 64 + ni * 16 + lrow;
                int b = m >> 11, s = m & (SEQ - 1), h = n >> 6, kk = n & (DK - 1);
                bfraw v = f2bf(acc[mi][ni][i] * scale);
                if (which == 2) O[(((b * NH + h) * DK) + kk) * SEQ + s] = v;
                else            O[(((b * NH + h) * SEQ) + s) * DK + kk] = v;
            }
}

// ---------------- flash MFMA attention: 8 waves, 128 q/block, KVBLK=128, mask-as-C-init ----------------
// KV tiles are 128 wide: half the barriers/loop iterations of the 64-wide version.
// Padding mask is pre-baked as float bias Mkb[s] = mask ? 0 : SENT and used as the QK MFMA
// C-initializer -- zero per-element mask VALU on far tiles (masked p = exp2(qk+SENT) ~= 1e-13,
// numerically equivalent). Causal compare only on the diagonal tile (t==0).
template<bool NEAR>
__device__ __forceinline__ void qk_soft(
        const bfraw* Kb, const bf16x8 qf[2], const float* Mkb,
        int kt0, int lrow, int quad, int q_ln, float& lsum, s16x4 pb[8]) {
    #pragma unroll
    for (int n = 0; n < 8; n++) {
        const int srow = n * 16 + lrow;
        bf16x8 kfa = *(const bf16x8*)&Kb[srow * 64 + ((quad ^ (lrow & 7)) << 3)];
        bf16x8 kfb = *(const bf16x8*)&Kb[srow * 64 + (((4 | quad) ^ (lrow & 7)) << 3)];
        f32x4 z = *(const f32x4*)&Mkb[kt0 + n * 16 + quad * 4];   // mask bias as C-init
        z = __builtin_amdgcn_mfma_f32_16x16x32_bf16(kfa, qf[0], z, 0, 0, 0);
        z = __builtin_amdgcn_mfma_f32_16x16x32_bf16(kfb, qf[1], z, 0, 0, 0);
        union { bf16x4 h; s16x4 s; } pk;
        #pragma unroll
        for (int i = 0; i < 4; i++) {
            float zz = z[i];
            if (NEAR) { int s = kt0 + n * 16 + quad * 4 + i; zz = (s > q_ln) ? zz : SENT; }
            float p = fexp2(zz);
            lsum += p;
            pk.h[i] = (__bf16)p;
        }
        pb[n] = pk.s;
    }
}

__global__ __launch_bounds__(512) void attn_flash(
        const bfraw* __restrict__ Qp, const bfraw* __restrict__ Kp, const bfraw* __restrict__ Vt,
        const int* __restrict__ mask, bfraw* __restrict__ Ctx) {
    __shared__ __align__(16) bfraw Ks[2][128 * 64];
    __shared__ __align__(16) bfraw Vs[2][64 * 128];
    __shared__ float Mkb[SEQ];
    __shared__ float Ps[8][64];
    __shared__ float Scol[64];
    const int bh = blockIdx.x, yy = blockIdx.y;
    const int gg = yy >> 3, jj = yy & 7;       // pairs {j, 15-j}: nt sum = 17, const work
    const int qt = gg ? (15 - jj) : jj;        // 128-row q tile
    const int b = bh >> 4, h = bh & 15;
    const int tid = threadIdx.x, wave = tid >> 6, lane = tid & 63;
    const int lrow = lane & 15, quad = lane >> 4;
    const int baseK = ((b * NH + h) * SEQ) * DK;
    const int baseV = ((b * NH + h) * DK) * SEQ;
    const int qbase = qt * 128 + wave * 16;
    const int q_ln  = qbase + lrow;            // this lane's q (col of S^T)
    const int diagKt = qt * 128;
    const int r8 = tid >> 3;                   // staging row 0..63
    const int c8 = tid & 7;                    // staging chunk
    const int kslot = (c8 ^ (r8 & 7)) << 3;    // K: rows r8 and r8+64 share slot (64%8==0)
    const int vslot0 = (c8 ^ (r8 & 7)) << 3;            // V chunk c8   (cols 0..63)
    const int vslot1 = ((8 | (c8 ^ (r8 & 7)))) << 3;    // V chunk c8+8 (cols 64..127)

    // ---- fused V prefix: Scol[d] = sum_{s<diagKt} V[d][s]
    const int d_v = tid & 63, part = tid >> 6;
    float pacc = 0.f;
    {
        const bfraw* vrow = Vt + baseV + d_v * SEQ;
        for (int s0 = part * 8; s0 < diagKt; s0 += 64) {
            u16x8 v = *(const u16x8*)(vrow + s0);
            #pragma unroll
            for (int e = 0; e < 8; e++) pacc += bf2f(v[e]);
        }
    }
    for (int i = tid; i < SEQ; i += 512) Mkb[i] = (mask[b * SEQ + i] != 0) ? 0.0f : SENT;
    Ps[part][d_v] = pacc;
    __syncthreads();
    if (tid < 64) {
        float sc = 0.f;
        #pragma unroll
        for (int p = 0; p < 8; p++) sc += Ps[p][tid];
        Scol[tid] = sc;
    }
    __syncthreads();

    bf16x8 qf[2];                              // B-operand: Q[q=lrow][k=ks*32+quad*8+j]
    qf[0] = *(const bf16x8*)(Qp + baseK + q_ln * DK + quad * 8);
    qf[1] = *(const bf16x8*)(Qp + baseK + q_ln * DK + 32 + quad * 8);

    f32x4 Oa[4];                               // O^T: row=d=nd*16+quad*4+i, col=q
    #pragma unroll
    for (int nd = 0; nd < 4; nd++)
        #pragma unroll
        for (int i = 0; i < 4; i++)
            Oa[nd][i] = PCONST * Scol[nd * 16 + quad * 4 + i];
    float lsum = 0.f;

    const int nt = (SEQ - diagKt) >> 7;        // 16 - qt >= 1
    int kt0 = diagKt;
    u16x8 k0 = *(const u16x8*)(Kp + baseK + (kt0 + r8) * DK + c8 * 8);
    u16x8 k1 = *(const u16x8*)(Kp + baseK + (kt0 + 64 + r8) * DK + c8 * 8);
    u16x8 v0 = *(const u16x8*)(Vt + baseV + r8 * SEQ + kt0 + c8 * 8);
    u16x8 v1 = *(const u16x8*)(Vt + baseV + r8 * SEQ + kt0 + 64 + c8 * 8);

    for (int t = 0; t < nt; t++, kt0 += 128) {
        bfraw* Kb = Ks[t & 1];
        bfraw* Vb = Vs[t & 1];
        *(u16x8*)&Kb[r8 * 64 + kslot]        = k0;
        *(u16x8*)&Kb[(64 + r8) * 64 + kslot] = k1;
        *(u16x8*)&Vb[r8 * 128 + vslot0]      = v0;
        *(u16x8*)&Vb[r8 * 128 + vslot1]      = v1;
        if (t + 1 < nt) {                      // prefetch overlaps barrier + compute
            const int kn = kt0 + 128;
            k0 = *(const u16x8*)(Kp + baseK + (kn + r8) * DK + c8 * 8);
            k1 = *(const u16x8*)(Kp + baseK + (kn + 64 + r8) * DK + c8 * 8);
            v0 = *(const u16x8*)(Vt + baseV + r8 * SEQ + kn + c8 * 8);
            v1 = *(const u16x8*)(Vt + baseV + r8 * SEQ + kn + 64 + c8 * 8);
        }
        __syncthreads();                       // single barrier per 128-tile (dbuf)

        s16x4 pb[8];
        if (t == 0) qk_soft<true >(Kb, qf, Mkb, kt0, lrow, quad, q_ln, lsum, pb);
        else        qk_soft<false>(Kb, qf, Mkb, kt0, lrow, quad, q_ln, lsum, pb);

        #pragma unroll
        for (int nd = 0; nd < 4; nd++) {
            const int d = nd * 16 + lrow;
            #pragma unroll
            for (int sc = 0; sc < 8; sc++) {
                const int ch = (sc << 1) | (quad >> 1);
                const int slot = (ch & 8) | ((ch & 7) ^ (d & 7));
                s16x4 vf = *(const s16x4*)&Vb[d * 128 + (slot << 3) + ((quad & 1) << 2)];
                Oa[nd] = mfma16(vf, pb[sc], Oa[nd]);
            }
        }
    }

    float r = lsum;
    r += __shfl_xor(r, 16, 64);
    r += __shfl_xor(r, 32, 64);
    const float inv = 1.0f / (r + (float)diagKt * PCONST);
    #pragma unroll
    for (int nd = 0; nd < 4; nd++) {
        u16x4 o;
        #pragma unroll
        for (int i = 0; i < 4; i++) o[i] = f2bf(Oa[nd][i] * inv);
        *(u16x4*)&Ctx[(b * SEQ + q_ln) * DIM + h * DK + nd * 16 + quad * 4] = o;
    }
}

// ---------------- output projection ----------------
__global__ __launch_bounds__(256) void out_gemm(
        const bfraw* __restrict__ Ctx, const bfraw* __restrict__ WoB, float* __restrict__ C) {
    const int m0 = blockIdx.x * 128, n0 = blockIdx.y * 128;
    f32x4 acc[4][4];
    gemm128(Ctx, WoB, m0, n0, acc);
    const int lane = threadIdx.x & 63, wave = threadIdx.x >> 6;
    const int lrow = lane & 15, quad = lane >> 4;
    const int wy = wave >> 1, wx = wave & 1;
    #pragma unroll
    for (int mi = 0; mi < 4; mi++)
        #pragma unroll
        for (int ni = 0; ni < 4; ni++)
            #pragma unroll
            for (int i = 0; i < 4; i++) {
                int m = m0 + wy * 64 + mi * 16 + quad * 4 + i;
                int n = n0 + wx * 64 + ni * 16 + lrow;
                C[m * DIM + n] = acc[mi][ni][i];
            }
}

// ---------------- residual + LayerNorm (fp32) ----------------
__global__ __launch_bounds__(256) void ln_kernel(
        const float* __restrict__ C, const float* __restrict__ Xq,
        const float* __restrict__ gamma, const float* __restrict__ beta,
        float* __restrict__ out) {
    __shared__ float rbuf[4];
    const int m = blockIdx.x, tid = threadIdx.x;
    const float* crow = C + m * DIM;
    const float* xrow = Xq + m * DIM;
    float v[4]; float s = 0.f, s2 = 0.f;
    #pragma unroll
    for (int i = 0; i < 4; i++) {
        int d = tid + (i << 8);
        float x = crow[d] + xrow[d];
        v[i] = x; s += x; s2 += x * x;
    }
    float S  = block_reduce(s,  rbuf, 1);
    float S2 = block_reduce(s2, rbuf, 1);
    float mu  = S * (1.0f / DIM);
    float var = S2 * (1.0f / DIM) - mu * mu;
    float rstd = rsqrtf(var + 1e-5f);
    #pragma unroll
    for (int i = 0; i < 4; i++) {
        int d = tid + (i << 8);
        out[m * DIM + d] = (v[i] - mu) * rstd * gamma[d] + beta[d];
    }
}

extern "C" void kernel_launch(void* const* d_in, const int* in_sizes, int n_in,
                              void* d_out, int out_size, void* d_ws, size_t ws_size,
                              hipStream_t stream) {
    const float* Xq    = (const float*)d_in[0];
    const float* Xk    = (const float*)d_in[1];
    const float* Xv    = (const float*)d_in[2];
    const int*   mask  = (const int*)  d_in[3];
    const float* Wq    = (const float*)d_in[4];
    const float* Wk    = (const float*)d_in[5];
    const float* Wv    = (const float*)d_in[6];
    const float* Wo    = (const float*)d_in[7];
    const float* gamma = (const float*)d_in[8];
    const float* beta  = (const float*)d_in[9];
    float* out = (float*)d_out;

    char* ws = (char*)d_ws;
    bfraw* Xb   = (bfraw*)(ws);                 // [0,24MB) dead after qkv
    bfraw* Wb   = (bfraw*)(ws + (24u << 20));
    bfraw* Qp   = (bfraw*)(ws + (32u << 20));
    bfraw* Kp   = (bfraw*)(ws + (40u << 20));
    bfraw* Vt   = (bfraw*)(ws + (48u << 20));
    bfraw* Ctx  = (bfraw*)(ws + (56u << 20));
    float* C    = (float*)(ws);                 // [0,16MB) reuses dead Xb

    dim3 blk(256);
    cvt_kernel<<<dim3(MROWS * DIM / (256 * 8), 7), blk, 0, stream>>>(Xq, Xk, Xv, Wq, Wk, Wv, Wo, Xb, Wb);
    qkv_gemm  <<<dim3(MROWS / 128, DIM / 128, 3),  blk, 0, stream>>>(Xb, Wb, Qp, Kp, Vt);
    attn_flash<<<dim3(BATCH * NH, SEQ / 128),      dim3(512), 0, stream>>>(Qp, Kp, Vt, mask, Ctx);
    out_gemm  <<<dim3(MROWS / 128, DIM / 128),     blk, 0, stream>>>(Ctx, Wb + 3 * (DIM * DIM), C);
    ln_kernel <<<dim3(MROWS),                      blk, 0, stream>>>(C, Xq, gamma, beta, out);
}